// Round 8
// baseline (138.183 us; speedup 1.0000x reference)
//
#include <hip/hip_runtime.h>
#include <hip/hip_bf16.h>

// LSTM: B=4096, T=200, I=2, H=64, O=2
// grid = 256 blocks x 512 threads (8 waves, 2 waves/SIMD, 1 block/CU).
// Block owns 16 batch rows as TWO independent 8-row tiles A (rows 0-7) and
// B (rows 8-15), advanced in alternating phases:
//   phase A(t): prefetch hB(t-1) -> regs | MFMA_A (operands prefetched) |
//               proj_B(t) | ACT_A | write hA(t) | barrier
//   phase B(t): prefetch hA(t)  -> regs | MFMA_B | proj_A(t+1) | ACT_B |
//               write hB(t) | barrier
// The h ds_read is issued a full phase ahead of its MFMA (always legal:
// the data was written before the preceding barrier), so LDS latency is
// off the critical path. Single-buffered hA/hB is race-free: __syncthreads
// drains lgkmcnt before a wave signals arrival, so all prefetch reads
// complete before any wave can pass the barrier and overwrite.
// Wave w: wq = w&3 -> unit quadrant [16wq,16wq+16); half = w>>2.
// A-fragment row map: A'[p] = hX[((p>>1)+half)&7] => D reg 0 of lane group g
// holds tile row 2g+half for every wave (STATIC index, branchless).
// MFMA runs M=16 on 8 real rows (upper half garbage, unused) — MFMA is cheap.
// Activation algebra (gate scales folded into weights: i,f,o: -log2e,
// g: 2*log2e):
//   c' = (c*P + (Eg-1)(1+Ef)) * rcp(P*(1+Ef)),  P = (1+Ei)(Eg+1)
//   h  = (Ec-1) * rcp((1+Eo)(Ec+1)),            Ec = 2^(2*log2e*c)
// => 5 exp + 2 rcp per (row,unit).

#define B_ 4096
#define T_ 200

typedef _Float16 half8 __attribute__((ext_vector_type(8)));
typedef float f32x4 __attribute__((ext_vector_type(4)));

#define K1f 1.4426950408889634f   // log2(e)
#define K2f 2.8853900817779268f   // 2*log2(e)

__global__ __launch_bounds__(512) void lstm_kernel(
    const float* __restrict__ x,     // [4096][200][2]
    const float* __restrict__ W_ih,  // [256][2]
    const float* __restrict__ W_hh,  // [256][64]
    const float* __restrict__ b_ih,  // [256]
    const float* __restrict__ b_hh,  // [256]
    const float* __restrict__ W_fc,  // [2][64]
    const float* __restrict__ b_fc,  // [2]
    float* __restrict__ out)         // [4096][2]
{
    __shared__ float xs[16][404];     // x tile (float4-aligned; cols 400..403 pad)
    __shared__ _Float16 hA[8][80];    // tile A hidden state (pad 64->80: conflict-free)
    __shared__ _Float16 hB[8][80];    // tile B hidden state
    __shared__ float wfc[130];        // W_fc (128) + b_fc (2)

    const int tid  = threadIdx.x;
    const int lane = tid & 63;
    const int w    = tid >> 6;      // wave 0..7
    const int wq   = w & 3;         // unit quadrant
    const int half = w >> 2;        // row-half selector
    const int cidx = lane & 15;
    const int grp  = lane >> 4;
    const int r0   = blockIdx.x * 16;

    // ---- stage x tile (coalesced float4): 16 rows x 100 float4 ----
    for (int i4 = tid; i4 < 1600; i4 += 512) {
        const int row = i4 / 100;
        const int j4  = i4 - row * 100;
        reinterpret_cast<float4*>(&xs[row][0])[j4] =
            reinterpret_cast<const float4*>(x + (size_t)(r0 + row) * 400)[j4];
    }
    // ---- zero hA/hB (incl. pad): 2*8*80 f16 = 640 dwords ----
    for (int i = tid; i < 320; i += 512)
        reinterpret_cast<unsigned int*>(&hA[0][0])[i] = 0u;
    for (int i = tid; i < 320; i += 512)
        reinterpret_cast<unsigned int*>(&hB[0][0])[i] = 0u;
    if (tid < 130) wfc[tid] = (tid < 128) ? W_fc[tid] : b_fc[tid - 128];

    // ---- W_hh B-fragments (f16, PRE-SCALED per gate) + x-proj coeffs ----
    // B-frag layout for mfma_f32_16x16x32_f16: lane l -> col = l&15, k = (l>>4)*8 + e
    half8 bfrag[4][2];
    float wi0[4], wi1[4], bs[4];
    const int u = wq * 16 + cidx;          // hidden unit owned by this lane
    #pragma unroll
    for (int m = 0; m < 4; ++m) {          // gate: 0=i,1=f,2=g,3=o (PyTorch order)
        const float sc = (m == 2) ? K2f : -K1f;
        const int g = m * 64 + u;
        wi0[m] = W_ih[g * 2 + 0] * sc;
        wi1[m] = W_ih[g * 2 + 1] * sc;
        bs[m]  = (b_ih[g] + b_hh[g]) * sc;
        #pragma unroll
        for (int kt = 0; kt < 2; ++kt) {
            const float* p = W_hh + g * 64 + kt * 32 + grp * 8;
            const float4 lo = reinterpret_cast<const float4*>(p)[0];
            const float4 hi = reinterpret_cast<const float4*>(p)[1];
            half8 f;
            f[0] = (_Float16)(lo.x * sc); f[1] = (_Float16)(lo.y * sc);
            f[2] = (_Float16)(lo.z * sc); f[3] = (_Float16)(lo.w * sc);
            f[4] = (_Float16)(hi.x * sc); f[5] = (_Float16)(hi.y * sc);
            f[6] = (_Float16)(hi.z * sc); f[7] = (_Float16)(hi.w * sc);
            bfrag[m][kt] = f;
        }
    }

    const int arow = ((cidx >> 1) + half) & 7;  // A' source row: A'[p]=hX[((p>>1)+half)&7]
    const int rowL = 2 * grp + half;            // local tile row this lane activates
    float cstA = 0.f, cstB = 0.f;               // cell states (tile A / tile B)

    __syncthreads();

    // One activation chain: pre-act args already exp2-scaled.
    #define ACT(pi, pf, pg, po, cst, hvout)                                    \
        {                                                                      \
            const float Ei = __builtin_amdgcn_exp2f(pi);                       \
            const float Ef = __builtin_amdgcn_exp2f(pf);                       \
            const float Eg = __builtin_amdgcn_exp2f(pg);                       \
            const float Eo = __builtin_amdgcn_exp2f(po);                       \
            const float fEf = 1.0f + Ef;                                       \
            const float P   = (1.0f + Ei) * (Eg + 1.0f);                       \
            const float r1  = __builtin_amdgcn_rcpf(P * fEf);                  \
            cst = fmaf(cst, P, (Eg - 1.0f) * fEf) * r1;                        \
            const float Ec = __builtin_amdgcn_exp2f(fminf(K2f * cst, 60.0f));  \
            const float r2 = __builtin_amdgcn_rcpf((1.0f + Eo) * (Ec + 1.0f)); \
            hvout = (Ec - 1.0f) * r2;                                          \
        }

    // A-fragments for both tiles; h(-1) = 0 for tile A.
    half8 aA0 = {0, 0, 0, 0, 0, 0, 0, 0}, aA1 = {0, 0, 0, 0, 0, 0, 0, 0};
    half8 aB0, aB1;

    // initial x-projection for tile A (t = 0)
    float projA[4], projB[4];
    {
        const float2 xv = *reinterpret_cast<const float2*>(&xs[rowL][0]);
        #pragma unroll
        for (int m = 0; m < 4; ++m)
            projA[m] = fmaf(xv.y, wi1[m], fmaf(xv.x, wi0[m], bs[m]));
    }

    for (int t = 0; t < T_; ++t) {
        // ================= phase A (tile A, step t) =================
        // prefetch tile B's h(t-1) (written before the previous barrier)
        aB0 = *reinterpret_cast<const half8*>(&hB[arow][grp * 8]);
        aB1 = *reinterpret_cast<const half8*>(&hB[arow][32 + grp * 8]);

        f32x4 acc[4];
        #pragma unroll
        for (int m = 0; m < 4; ++m) {
            f32x4 c = {projA[m], projA[m], projA[m], projA[m]};
            c = __builtin_amdgcn_mfma_f32_16x16x32_f16(aA0, bfrag[m][0], c, 0, 0, 0);
            c = __builtin_amdgcn_mfma_f32_16x16x32_f16(aA1, bfrag[m][1], c, 0, 0, 0);
            acc[m] = c;
        }
        {   // proj for tile B, step t (in MFMA shadow)
            const float2 xv = *reinterpret_cast<const float2*>(&xs[8 + rowL][2 * t]);
            #pragma unroll
            for (int m = 0; m < 4; ++m)
                projB[m] = fmaf(xv.y, wi1[m], fmaf(xv.x, wi0[m], bs[m]));
        }
        {
            float hv;
            ACT(acc[0][0], acc[1][0], acc[2][0], acc[3][0], cstA, hv);
            hA[rowL][u] = (_Float16)hv;
        }
        __syncthreads();   // barrier 1: hA(t) visible; all aB prefetches done

        // ================= phase B (tile B, step t) =================
        // prefetch tile A's h(t) (written before barrier 1)
        aA0 = *reinterpret_cast<const half8*>(&hA[arow][grp * 8]);
        aA1 = *reinterpret_cast<const half8*>(&hA[arow][32 + grp * 8]);

        #pragma unroll
        for (int m = 0; m < 4; ++m) {
            f32x4 c = {projB[m], projB[m], projB[m], projB[m]};
            c = __builtin_amdgcn_mfma_f32_16x16x32_f16(aB0, bfrag[m][0], c, 0, 0, 0);
            c = __builtin_amdgcn_mfma_f32_16x16x32_f16(aB1, bfrag[m][1], c, 0, 0, 0);
            acc[m] = c;
        }
        {   // proj for tile A, step t+1 (xs padded: t=199 reads cols 400/401)
            const float2 xv = *reinterpret_cast<const float2*>(&xs[rowL][2 * t + 2]);
            #pragma unroll
            for (int m = 0; m < 4; ++m)
                projA[m] = fmaf(xv.y, wi1[m], fmaf(xv.x, wi0[m], bs[m]));
        }
        {
            float hv;
            ACT(acc[0][0], acc[1][0], acc[2][0], acc[3][0], cstB, hv);
            hB[rowL][u] = (_Float16)hv;
        }
        __syncthreads();   // barrier 2: hB(t) visible; all aA prefetches done
    }

    // ---- FC epilogue: hA/hB hold h(t=199) ----
    if (tid < 32) {
        const int r = tid & 15;
        const int o = tid >> 4;
        const _Float16* hsrc = (r < 8) ? &hA[r][0] : &hB[r - 8][0];
        float s = wfc[128 + o];
        #pragma unroll
        for (int k = 0; k < 64; ++k)
            s = fmaf(wfc[o * 64 + k], (float)hsrc[k], s);
        out[(size_t)(r0 + r) * 2 + o] = s;
    }
}

extern "C" void kernel_launch(void* const* d_in, const int* in_sizes, int n_in,
                              void* d_out, int out_size, void* d_ws, size_t ws_size,
                              hipStream_t stream) {
    const float* x    = (const float*)d_in[0];
    const float* W_ih = (const float*)d_in[1];
    const float* W_hh = (const float*)d_in[2];
    const float* b_ih = (const float*)d_in[3];
    const float* b_hh = (const float*)d_in[4];
    const float* W_fc = (const float*)d_in[5];
    const float* b_fc = (const float*)d_in[6];
    float* out = (float*)d_out;

    lstm_kernel<<<B_ / 16, 512, 0, stream>>>(x, W_ih, W_hh, b_ih, b_hh, W_fc, b_fc, out);
}

// Round 11
// 119.478 us; speedup vs baseline: 1.1566x; 1.1566x over previous
//
#include <hip/hip_runtime.h>
#include <hip/hip_bf16.h>

// LSTM: B=4096, T=200, I=2, H=64, O=2
// grid = 256 blocks x 512 threads (8 waves, 2 waves/SIMD, 1 block/CU).
// WAVE-SPECIALIZED PIPELINE: block's 16 rows = two INDEPENDENT 8-row LSTMs:
//   group A (waves 0-3, rows 0-7), group B (waves 4-7, rows 8-15).
// Each SIMD hosts one A-wave and one B-wave, running HALF A STEP apart:
//   interval 2k  : A does P1(k)   [ACT+write]   | B does P0(k)   [read+MFMA]
//   interval 2k+1: A does P0(k+1) [read+MFMA]   | B does P1(k)   [ACT+write]
// P0 (low issue, high latency) overlaps the partner's P1 (high trans issue).
// Groups share no data; the block barrier is only a clock. Schedules (equal
// barrier counts, writes always a full barrier before the paired reads):
//   A: P0(0); bar; { P1(k); bar; P0(k+1); bar } k=0..199
//   B:        bar; { P0(k); bar; P1(k); bar }   k=0..199
// Wave w: quadrant wq=w&3 -> units [16wq,16wq+16). A-frag row map
// A'[p] = hX[p>>1] (each row duplicated): D reg r in lane-group g = local row
// 2g+(r>>1) -> regs 0,2 give the lane's two rows STATICALLY. No garbage rows.
// R9 lesson: non-pow2 masked zeroing skipped dwords -> NaN.
// R10 lesson: the per-buffer dword count was HALVED (8x72 f16 = 576 f16 =
// 288 dwords, not 144) -> rows 4-7 of hA/hB uninitialized -> NaN. Fixed.
// Activation algebra (gate scales folded into weights: i,f,o: -log2e,
// g: 2*log2e):
//   c' = (c*P + (Eg-1)(1+Ef)) * rcp(P*(1+Ef)),  P = (1+Ei)(Eg+1)
//   h  = (Ec-1) * rcp((1+Eo)(Ec+1)),            Ec = 2^(2*log2e*c)
// => 5 exp + 2 rcp per (row,unit).

#define B_ 4096
#define T_ 200

typedef _Float16 half8 __attribute__((ext_vector_type(8)));
typedef float f32x4 __attribute__((ext_vector_type(4)));

#define K1f 1.4426950408889634f   // log2(e)
#define K2f 2.8853900817779268f   // 2*log2(e)

__global__ __launch_bounds__(512) void lstm_kernel(
    const float* __restrict__ x,     // [4096][200][2]
    const float* __restrict__ W_ih,  // [256][2]
    const float* __restrict__ W_hh,  // [256][64]
    const float* __restrict__ b_ih,  // [256]
    const float* __restrict__ b_hh,  // [256]
    const float* __restrict__ W_fc,  // [2][64]
    const float* __restrict__ b_fc,  // [2]
    float* __restrict__ out)         // [4096][2]
{
    __shared__ float xs[16][404];    // x tile (float4-aligned; cols 400..403 pad)
    __shared__ _Float16 hA[8][72];   // group A hidden state (rows 0-7)
    __shared__ _Float16 hB[8][72];   // group B hidden state (rows 8-15)
    __shared__ float wfc[130];       // W_fc (128) + b_fc (2)

    const int tid  = threadIdx.x;
    const int lane = tid & 63;
    const int w    = tid >> 6;      // wave 0..7
    const int wq   = w & 3;         // unit quadrant
    const int cidx = lane & 15;
    const int grp  = lane >> 4;
    const int r0   = blockIdx.x * 16;

    // ---- stage x tile (coalesced float4): 16 rows x 100 float4 ----
    for (int i4 = tid; i4 < 1600; i4 += 512) {
        const int row = i4 / 100;
        const int j4  = i4 - row * 100;
        reinterpret_cast<float4*>(&xs[row][0])[j4] =
            reinterpret_cast<const float4*>(x + (size_t)(r0 + row) * 400)[j4];
    }
    // ---- zero xs pad columns 400..403 (dead t=200 prefetch reads them) ----
    if (tid < 64) xs[tid >> 2][400 + (tid & 3)] = 0.f;
    // ---- zero hA and hB: 8*72 f16 = 576 f16 = 288 DWORDS each ----
    for (int i = tid; i < 288; i += 512)
        reinterpret_cast<unsigned int*>(&hA[0][0])[i] = 0u;
    for (int i = tid; i < 288; i += 512)
        reinterpret_cast<unsigned int*>(&hB[0][0])[i] = 0u;
    if (tid < 130) wfc[tid] = (tid < 128) ? W_fc[tid] : b_fc[tid - 128];

    // ---- W_hh B-fragments (f16, PRE-SCALED per gate) + x-proj coeffs ----
    // B-frag layout for mfma_f32_16x16x32_f16: lane l -> col = l&15, k = (l>>4)*8 + e
    half8 bfrag[4][2];
    float wi0[4], wi1[4], bs[4];
    const int u = wq * 16 + cidx;          // hidden unit owned by this lane
    #pragma unroll
    for (int m = 0; m < 4; ++m) {          // gate: 0=i,1=f,2=g,3=o (PyTorch order)
        const float sc = (m == 2) ? K2f : -K1f;
        const int g = m * 64 + u;
        wi0[m] = W_ih[g * 2 + 0] * sc;
        wi1[m] = W_ih[g * 2 + 1] * sc;
        bs[m]  = (b_ih[g] + b_hh[g]) * sc;
        #pragma unroll
        for (int kt = 0; kt < 2; ++kt) {
            const float* p = W_hh + g * 64 + kt * 32 + grp * 8;
            const float4 lo = reinterpret_cast<const float4*>(p)[0];
            const float4 hi = reinterpret_cast<const float4*>(p)[1];
            half8 f;
            f[0] = (_Float16)(lo.x * sc); f[1] = (_Float16)(lo.y * sc);
            f[2] = (_Float16)(lo.z * sc); f[3] = (_Float16)(lo.w * sc);
            f[4] = (_Float16)(hi.x * sc); f[5] = (_Float16)(hi.y * sc);
            f[6] = (_Float16)(hi.z * sc); f[7] = (_Float16)(hi.w * sc);
            bfrag[m][kt] = f;
        }
    }

    const int arow = cidx >> 1;      // A' source row: A'[p] = hX[p>>1]
    const int rowL = 2 * grp;        // first LOCAL row this lane activates
    float cst0 = 0.f, cst1 = 0.f;    // cell states for local rows rowL, rowL+1
    f32x4 acc[4];                    // gate accumulators, carried across a barrier

    __syncthreads();                 // staging barrier (bar 0)

    // One activation chain: pre-act args already exp2-scaled.
    #define ACT(pi, pf, pg, po, cst, hvout)                                    \
        {                                                                      \
            const float Ei = __builtin_amdgcn_exp2f(pi);                       \
            const float Ef = __builtin_amdgcn_exp2f(pf);                       \
            const float Eg = __builtin_amdgcn_exp2f(pg);                       \
            const float Eo = __builtin_amdgcn_exp2f(po);                       \
            const float fEf = 1.0f + Ef;                                       \
            const float P   = (1.0f + Ei) * (Eg + 1.0f);                       \
            const float r1  = __builtin_amdgcn_rcpf(P * fEf);                  \
            cst = fmaf(cst, P, (Eg - 1.0f) * fEf) * r1;                        \
            const float Ec = __builtin_amdgcn_exp2f(fminf(K2f * cst, 60.0f));  \
            const float r2 = __builtin_amdgcn_rcpf((1.0f + Eo) * (Ec + 1.0f)); \
            hvout = (Ec - 1.0f) * r2;                                          \
        }

    // P0: read h, x-proj, 8 MFMAs -> acc. P1: 2 ACT chains, write h.
    #define PHASE0(hX, gbase, t)                                               \
        {                                                                      \
            const half8 a0 = *reinterpret_cast<const half8*>(&hX[arow][grp * 8]);      \
            const half8 a1 = *reinterpret_cast<const half8*>(&hX[arow][32 + grp * 8]); \
            const float2 xv0 = *reinterpret_cast<const float2*>(&xs[(gbase) + rowL][2 * (t)]);     \
            const float2 xv1 = *reinterpret_cast<const float2*>(&xs[(gbase) + rowL + 1][2 * (t)]); \
            _Pragma("unroll")                                                  \
            for (int m = 0; m < 4; ++m) {                                      \
                const float p0 = fmaf(xv0.y, wi1[m], fmaf(xv0.x, wi0[m], bs[m])); \
                const float p1 = fmaf(xv1.y, wi1[m], fmaf(xv1.x, wi0[m], bs[m])); \
                f32x4 c = {p0, p0, p1, p1};                                    \
                c = __builtin_amdgcn_mfma_f32_16x16x32_f16(a0, bfrag[m][0], c, 0, 0, 0); \
                c = __builtin_amdgcn_mfma_f32_16x16x32_f16(a1, bfrag[m][1], c, 0, 0, 0); \
                acc[m] = c;                                                    \
            }                                                                  \
        }

    #define PHASE1(hX)                                                         \
        {                                                                      \
            float hv0, hv1;                                                    \
            ACT(acc[0][0], acc[1][0], acc[2][0], acc[3][0], cst0, hv0);        \
            ACT(acc[0][2], acc[1][2], acc[2][2], acc[3][2], cst1, hv1);        \
            hX[rowL][u]     = (_Float16)hv0;                                   \
            hX[rowL + 1][u] = (_Float16)hv1;                                   \
        }

    if (w < 4) {
        // ---------------- group A: rows 0-7 ----------------
        PHASE0(hA, 0, 0);
        __syncthreads();                       // bar 1
        for (int t = 0; t < T_; ++t) {
            PHASE1(hA);                        // ACT step t, write hA(t)
            __syncthreads();
            PHASE0(hA, 0, t + 1);              // read hA(t), MFMA step t+1
            __syncthreads();                   // (t=199: reads zeroed xs pad; acc unused)
        }
    } else {
        // ---------------- group B: rows 8-15 ----------------
        __syncthreads();                       // bar 1
        for (int t = 0; t < T_; ++t) {
            PHASE0(hB, 8, t);                  // read hB(t-1), MFMA step t
            __syncthreads();
            PHASE1(hB);                        // ACT step t, write hB(t)
            __syncthreads();
        }
    }

    // ---- FC epilogue: hA/hB hold h(t=199); last barrier already passed ----
    if (tid < 32) {
        const int r = tid & 15;
        const int o = tid >> 4;
        const _Float16* hsrc = (r < 8) ? &hA[r][0] : &hB[r - 8][0];
        float s = wfc[128 + o];
        #pragma unroll
        for (int k = 0; k < 64; ++k)
            s = fmaf(wfc[o * 64 + k], (float)hsrc[k], s);
        out[(size_t)(r0 + r) * 2 + o] = s;
    }
}

extern "C" void kernel_launch(void* const* d_in, const int* in_sizes, int n_in,
                              void* d_out, int out_size, void* d_ws, size_t ws_size,
                              hipStream_t stream) {
    const float* x    = (const float*)d_in[0];
    const float* W_ih = (const float*)d_in[1];
    const float* W_hh = (const float*)d_in[2];
    const float* b_ih = (const float*)d_in[3];
    const float* b_hh = (const float*)d_in[4];
    const float* W_fc = (const float*)d_in[5];
    const float* b_fc = (const float*)d_in[6];
    float* out = (float*)d_out;

    lstm_kernel<<<B_ / 16, 512, 0, stream>>>(x, W_ih, W_hh, b_ih, b_hh, W_fc, b_fc, out);
}